// Round 8
// baseline (379.493 us; speedup 1.0000x reference)
//
#include <hip/hip_runtime.h>

using uint = unsigned int;
typedef short bf16x8 __attribute__((ext_vector_type(8)));
typedef _Float16 f16x8 __attribute__((ext_vector_type(8)));
typedef float f32x4 __attribute__((ext_vector_type(4)));
typedef int i32x4 __attribute__((ext_vector_type(4)));
typedef int i32x8 __attribute__((ext_vector_type(8)));

static constexpr int Cc = 512;
static constexpr int Nn = 4096;               // H*W
static constexpr size_t NC = (size_t)Nn * Cc; // 2097152 elements
static constexpr size_t SN = (size_t)Nn * Nn; // 16777216 elements

__device__ __forceinline__ unsigned short f2bf(float f) {
    unsigned int u = __builtin_bit_cast(unsigned int, f);
    u = (u + 0x7fff + ((u >> 16) & 1)) >> 16;
    return (unsigned short)u;
}
__device__ __forceinline__ unsigned short f2h(float f) {
    _Float16 h = (_Float16)f;
    return __builtin_bit_cast(unsigned short, h);
}

__device__ __forceinline__ void gll16(const void* g, void* l) {
    __builtin_amdgcn_global_load_lds(
        (const __attribute__((address_space(1))) void*)g,
        (__attribute__((address_space(3))) void*)l, 16, 0, 0);
}

// Read one 32-byte k-run fragment (granules 2*kq, 2*kq+1 of a 128B LDS row,
// XOR-swizzled by row&7) as 8 dwords for the K=128 scaled MFMA.
__device__ __forceinline__ i32x8 ldsfrag(const unsigned char* lds, int R, int kq) {
    int x = (R & 7) << 4;
    i32x4 lo4 = *(const i32x4*)(lds + R * 128 + (((kq * 2) << 4) ^ x));
    i32x4 hi4 = *(const i32x4*)(lds + R * 128 + (((kq * 2 + 1) << 4) ^ x));
    return __builtin_shufflevector(lo4, hi4, 0, 1, 2, 3, 4, 5, 6, 7);
}

// MX-scaled fp8 MFMA with unit scales (E8M0 bias 127) == plain fp8 matmul at 2x rate
__device__ __forceinline__ f32x4 mfma8(i32x8 a, i32x8 b, f32x4 c) {
    return __builtin_amdgcn_mfma_scale_f32_16x16x128_f8f6f4(
        a, b, c, 0, 0, 0, 0x7F7F7F7F, 0, 0x7F7F7F7F);
}

// ---------------- fp32 -> bf16 weight convert ----------------
__global__ void cvt_kernel(const float* __restrict__ in, unsigned short* __restrict__ out, int n4) {
    int i = blockIdx.x * blockDim.x + threadIdx.x;
    if (i < n4) {
        float4 v = ((const float4*)in)[i];
        out[i * 4 + 0] = f2bf(v.x);
        out[i * 4 + 1] = f2bf(v.y);
        out[i * 4 + 2] = f2bf(v.z);
        out[i * 4 + 3] = f2bf(v.w);
    }
}

// ---------------- zero the row-sum accumulator ----------------
__global__ void zero_kernel(float* __restrict__ p, int n4) {
    int i = blockIdx.x * blockDim.x + threadIdx.x;
    if (i < n4) ((float4*)p)[i] = make_float4(0.f, 0.f, 0.f, 0.f);
}

// ---------------- GN pass 1: stats per (b,g) ----------------
__global__ void gn_stats_kernel(const float* __restrict__ x, float* __restrict__ meanb,
                                float* __restrict__ rsb) {
    int bg = blockIdx.x; // 128 = B*32
    const float* slab = x + (size_t)bg * 16 * Nn;
    const float4* s4 = (const float4*)slab;
    int t = threadIdx.x; // 256
    float s1 = 0.f, s2 = 0.f;
#pragma unroll 8
    for (int k = 0; k < 64; ++k) {
        float4 v = s4[k * 256 + t];
        s1 += v.x + v.y + v.z + v.w;
        s2 += v.x * v.x + v.y * v.y + v.z * v.z + v.w * v.w;
    }
#pragma unroll
    for (int o = 32; o > 0; o >>= 1) { s1 += __shfl_down(s1, o); s2 += __shfl_down(s2, o); }
    __shared__ float r1[4], r2[4];
    int wv_ = t >> 6, ln = t & 63;
    if (ln == 0) { r1[wv_] = s1; r2[wv_] = s2; }
    __syncthreads();
    if (t == 0) {
        float a1 = r1[0] + r1[1] + r1[2] + r1[3];
        float a2 = r2[0] + r2[1] + r2[2] + r2[3];
        float mean = a1 * (1.f / 65536.f);
        float var = a2 * (1.f / 65536.f) - mean * mean;
        meanb[bg] = mean;
        rsb[bg] = rsqrtf(var + 1e-6f);
    }
}

// ---------------- GN pass 2: normalize + transpose via LDS tile ----------------
__global__ __launch_bounds__(256) void gn_norm_kernel(
    const float* __restrict__ x, const float* __restrict__ meanb, const float* __restrict__ rsb,
    const float* __restrict__ gamma, const float* __restrict__ beta,
    unsigned short* __restrict__ h_t) {
    __shared__ float tile[64][65];
    int n0 = blockIdx.x * 64, c0 = blockIdx.y * 64, b = blockIdx.z;
    int t = threadIdx.x;
    const float* xb = x + (size_t)b * Cc * Nn;
#pragma unroll
    for (int j = 0; j < 4; ++j) {
        int i = j * 256 + t;
        int c = i >> 4;       // 0..63
        int n4 = i & 15;      // float4 index within row
        int cg = c0 + c;
        float4 v = ((const float4*)(xb + (size_t)cg * Nn + n0))[n4];
        int g = cg >> 4;
        float mean = meanb[b * 32 + g], rs = rsb[b * 32 + g];
        float ga = gamma[cg] * rs;
        float be = beta[cg] - mean * ga;
        tile[n4 * 4 + 0][c] = v.x * ga + be;
        tile[n4 * 4 + 1][c] = v.y * ga + be;
        tile[n4 * 4 + 2][c] = v.z * ga + be;
        tile[n4 * 4 + 3][c] = v.w * ga + be;
    }
    __syncthreads();
    int n = t >> 2;                 // 0..63
    int cpart = (t & 3) * 16;       // 0,16,32,48
    unsigned short o[16];
#pragma unroll
    for (int q = 0; q < 16; ++q) o[q] = f2bf(tile[n][cpart + q]);
    unsigned short* dst = h_t + (size_t)b * NC + (size_t)(n0 + n) * Cc + c0 + cpart;
    ((uint4*)dst)[0] = ((uint4*)o)[0];
    ((uint4*)dst)[1] = ((uint4*)o)[1];
}

// ---------------- bf16 GEMM: out[M,N] = (A[M,K] * Bt[N,K]^T + bias) * alpha (+res) --------
// Block tile BM x 128, 4 waves as 2x2, wave tile (BM/2) x 64. BK=64.
// DT: 0 bf16, 1 fp16. BIAS_MODE: 0 none, 1 bias[m], 2 bias[n].
// OUT_MODE: 0 fp32, 1 bf16, 2 fp16, 3 fp8(e4m3) natural layout.
template <int BM, int DT, int BIAS_MODE, int OUT_MODE, int HAS_RES>
__global__ __launch_bounds__(256, 2) void gemm_bt(
    const unsigned short* __restrict__ A, int lda, size_t sA,
    const unsigned short* __restrict__ Bt, int ldb, size_t sB,
    void* __restrict__ outp, int ldc, size_t sC,
    const float* __restrict__ bias,
    const float* __restrict__ res, size_t sR,
    int K, float alpha) {
    constexpr int MT = BM / 32;  // m-fragments per wave (4 or 8)
    __shared__ unsigned short lA[BM * 64];
    __shared__ unsigned short lB[128 * 64];
    int z = blockIdx.z;
    A += (size_t)z * sA;
    Bt += (size_t)z * sB;
    int m0 = blockIdx.y * BM, n0 = blockIdx.x * 128;
    int t = threadIdx.x;
    int lane = t & 63, wave = t >> 6;
    int wm = wave >> 1, wn = wave & 1;
    int lo = lane & 15, quad = lane >> 4;

    f32x4 acc[MT][4];
#pragma unroll
    for (int a1 = 0; a1 < MT; ++a1)
#pragma unroll
        for (int a2 = 0; a2 < 4; ++a2) acc[a1][a2] = (f32x4){0.f, 0.f, 0.f, 0.f};

    for (int k0 = 0; k0 < K; k0 += 64) {
#pragma unroll
        for (int p = 0; p < MT; ++p) {
            int ci = p * 256 + t;
            int row = ci >> 3;
            int gs = (ci ^ row) & 7;  // swizzled granule
            gll16(A + (size_t)(m0 + row) * lda + k0 + gs * 8, &lA[(size_t)ci * 8]);
        }
#pragma unroll
        for (int p = 0; p < 4; ++p) {
            int ci = p * 256 + t;
            int row = ci >> 3;
            int gs = (ci ^ row) & 7;
            gll16(Bt + (size_t)(n0 + row) * ldb + k0 + gs * 8, &lB[(size_t)ci * 8]);
        }
        __syncthreads();
#pragma unroll
        for (int ks = 0; ks < 2; ++ks) {
            int G = quad + ks * 4;  // granule index (8 halfs each)
            bf16x8 af[MT], bfr[4];
#pragma unroll
            for (int mt = 0; mt < MT; ++mt) {
                int R = wm * (BM / 2) + mt * 16 + lo;
                af[mt] = *(const bf16x8*)&lA[R * 64 + (((G ^ R) & 7) << 3)];
            }
#pragma unroll
            for (int nt = 0; nt < 4; ++nt) {
                int R = wn * 64 + nt * 16 + lo;
                bfr[nt] = *(const bf16x8*)&lB[R * 64 + (((G ^ R) & 7) << 3)];
            }
#pragma unroll
            for (int mt = 0; mt < MT; ++mt)
#pragma unroll
                for (int nt = 0; nt < 4; ++nt) {
                    if (DT == 0)
                        acc[mt][nt] = __builtin_amdgcn_mfma_f32_16x16x32_bf16(af[mt], bfr[nt], acc[mt][nt], 0, 0, 0);
                    else
                        acc[mt][nt] = __builtin_amdgcn_mfma_f32_16x16x32_f16(
                            __builtin_bit_cast(f16x8, af[mt]), __builtin_bit_cast(f16x8, bfr[nt]),
                            acc[mt][nt], 0, 0, 0);
                }
        }
        __syncthreads();
    }

    size_t zc = (size_t)z * sC;
    float* outf = (float*)outp + zc;
    unsigned short* outb = (unsigned short*)outp + zc;
    unsigned char* outc = (unsigned char*)outp + zc;
    const float* resz = HAS_RES ? res + (size_t)z * sR : nullptr;

#pragma unroll
    for (int mt = 0; mt < MT; ++mt) {
#pragma unroll
        for (int nt = 0; nt < 4; ++nt) {
            int row = m0 + wm * (BM / 2) + mt * 16 + quad * 4;
            int col = n0 + wn * 64 + nt * 16 + lo;
            float bn = (BIAS_MODE == 2) ? bias[col] : 0.f;
#pragma unroll
            for (int r = 0; r < 4; ++r) {
                float vv = acc[mt][nt][r];
                if (BIAS_MODE == 1) vv += bias[row + r];
                if (BIAS_MODE == 2) vv += bn;
                vv *= alpha;
                if (OUT_MODE == 3) {
                    float e = fmaxf(fminf(vv, 448.f), -448.f);
                    int pk = __builtin_amdgcn_cvt_pk_fp8_f32(e, e, 0, false);
                    outc[(size_t)(row + r) * ldc + col] = (unsigned char)(pk & 0xff);
                } else {
                    size_t off = (size_t)(row + r) * ldc + col;
                    if (HAS_RES) vv += resz[off];
                    if (OUT_MODE == 0) outf[off] = vv;
                    else if (OUT_MODE == 1) outb[off] = f2bf(vv);
                    else outb[off] = f2h(vv);
                }
            }
        }
    }
}

// ---------------- QK: S = fp8(exp((Q.K^T)*alpha - 2)), lsum += row sums ----
// Q,K fp8 [B,N,C] natural. Block tile 256x128, waves 2x2, BK=128.
// K=128 MX-scaled MFMA (unit scales): one k-step per tile, 2x fp8 rate.
__global__ __launch_bounds__(256, 2) void qk_fp8(
    const unsigned char* __restrict__ Q, const unsigned char* __restrict__ Kt,
    unsigned char* __restrict__ S, float* __restrict__ lsum, float alpha) {
    __shared__ unsigned char lA[256 * 128]; // 32 KB
    __shared__ unsigned char lB[128 * 128]; // 16 KB
    int z = blockIdx.z;
    Q += (size_t)z * NC;
    Kt += (size_t)z * NC;
    S += (size_t)z * SN;
    lsum += (size_t)z * Nn;
    int m0 = blockIdx.y * 256, n0 = blockIdx.x * 128;
    int t = threadIdx.x;
    int lane = t & 63, wave = t >> 6;
    int wm = wave >> 1, wn = wave & 1;
    int lo = lane & 15, quad = lane >> 4;

    f32x4 acc[8][4];
#pragma unroll
    for (int a1 = 0; a1 < 8; ++a1)
#pragma unroll
        for (int a2 = 0; a2 < 4; ++a2) acc[a1][a2] = (f32x4){0.f, 0.f, 0.f, 0.f};

    for (int k0 = 0; k0 < Cc; k0 += 128) {
#pragma unroll
        for (int p = 0; p < 8; ++p) {
            int ci = p * 256 + t;
            int row = ci >> 3, g = ci & 7;
            int gs = g ^ (row & 7);
            gll16(Q + (size_t)(m0 + row) * Cc + k0 + gs * 16, &lA[ci * 16]);
        }
#pragma unroll
        for (int p = 0; p < 4; ++p) {
            int ci = p * 256 + t;
            int row = ci >> 3, g = ci & 7;
            int gs = g ^ (row & 7);
            gll16(Kt + (size_t)(n0 + row) * Cc + k0 + gs * 16, &lB[ci * 16]);
        }
        __syncthreads();
        i32x8 bq[4];
#pragma unroll
        for (int nt = 0; nt < 4; ++nt)
            bq[nt] = ldsfrag(lB, wn * 64 + nt * 16 + lo, quad);
#pragma unroll
        for (int mt = 0; mt < 8; ++mt) {
            i32x8 aq = ldsfrag(lA, wm * 128 + mt * 16 + lo, quad);
#pragma unroll
            for (int nt = 0; nt < 4; ++nt)
                acc[mt][nt] = mfma8(aq, bq[nt], acc[mt][nt]);
        }
        __syncthreads();
    }

#pragma unroll
    for (int mt = 0; mt < 8; ++mt) {
        int row = m0 + wm * 128 + mt * 16 + quad * 4;
        float rsum[4] = {0.f, 0.f, 0.f, 0.f};
#pragma unroll
        for (int nt = 0; nt < 4; ++nt) {
            int col = n0 + wn * 64 + nt * 16 + lo;
#pragma unroll
            for (int r = 0; r < 4; ++r) {
                float e = __expf(acc[mt][nt][r] * alpha - 2.f);
                e = fminf(e, 448.f);
                int pk = __builtin_amdgcn_cvt_pk_fp8_f32(e, e, 0, false);
                S[(size_t)(row + r) * Nn + col] = (unsigned char)(pk & 0xff);
                rsum[r] += e;
            }
        }
#pragma unroll
        for (int o = 1; o < 16; o <<= 1) {
#pragma unroll
            for (int r = 0; r < 4; ++r) rsum[r] += __shfl_xor(rsum[r], o);
        }
        if (lo == 0) {
#pragma unroll
            for (int r = 0; r < 4; ++r) atomicAdd(&lsum[row + r], rsum[r]);
        }
    }
}

// ---------------- PV: o_t[m,c] = (sum_j P[m,j] V[c,j]) / lsum[m] ----------------
// S [B,N,N] and V [B,C,N] natural fp8. K=128 MX-scaled MFMA, BK=128, 128x128 tile.
__global__ __launch_bounds__(256, 3) void pv_fp8(
    const unsigned char* __restrict__ S, const unsigned char* __restrict__ V,
    const float* __restrict__ lsum, unsigned short* __restrict__ o_t) {
    __shared__ unsigned char lA[128 * 128];
    __shared__ unsigned char lB[128 * 128];
    int z = blockIdx.z;
    S += (size_t)z * SN;
    V += (size_t)z * NC;
    lsum += (size_t)z * Nn;
    o_t += (size_t)z * NC;
    int m0 = blockIdx.y * 128, n0 = blockIdx.x * 128;
    int t = threadIdx.x;
    int lane = t & 63, wave = t >> 6;
    int wm = wave >> 1, wn = wave & 1;
    int lo = lane & 15, quad = lane >> 4;

    f32x4 acc[4][4];
#pragma unroll
    for (int a1 = 0; a1 < 4; ++a1)
#pragma unroll
        for (int a2 = 0; a2 < 4; ++a2) acc[a1][a2] = (f32x4){0.f, 0.f, 0.f, 0.f};

    for (int k0 = 0; k0 < Nn; k0 += 128) {
#pragma unroll
        for (int p = 0; p < 4; ++p) {
            int ci = p * 256 + t;
            int row = ci >> 3, g = ci & 7;
            int gs = g ^ (row & 7);
            gll16(S + (size_t)(m0 + row) * Nn + k0 + gs * 16, &lA[ci * 16]);
        }
#pragma unroll
        for (int p = 0; p < 4; ++p) {
            int ci = p * 256 + t;
            int row = ci >> 3, g = ci & 7;
            int gs = g ^ (row & 7);
            gll16(V + (size_t)(n0 + row) * Nn + k0 + gs * 16, &lB[ci * 16]);
        }
        __syncthreads();
        i32x8 bq[4];
#pragma unroll
        for (int nt = 0; nt < 4; ++nt)
            bq[nt] = ldsfrag(lB, wn * 64 + nt * 16 + lo, quad);
#pragma unroll
        for (int mt = 0; mt < 4; ++mt) {
            i32x8 aq = ldsfrag(lA, wm * 64 + mt * 16 + lo, quad);
#pragma unroll
            for (int nt = 0; nt < 4; ++nt)
                acc[mt][nt] = mfma8(aq, bq[nt], acc[mt][nt]);
        }
        __syncthreads();
    }

#pragma unroll
    for (int mt = 0; mt < 4; ++mt)
#pragma unroll
        for (int nt = 0; nt < 4; ++nt) {
            int row = m0 + wm * 64 + mt * 16 + quad * 4;
            int col = n0 + wn * 64 + nt * 16 + lo;
#pragma unroll
            for (int r = 0; r < 4; ++r) {
                float vv = acc[mt][nt][r] / lsum[row + r];
                o_t[(size_t)(row + r) * Cc + col] = f2bf(vv);
            }
        }
}

extern "C" void kernel_launch(void* const* d_in, const int* in_sizes, int n_in,
                              void* d_out, int out_size, void* d_ws, size_t ws_size,
                              hipStream_t stream) {
    const float* x     = (const float*)d_in[0];
    const float* gamma = (const float*)d_in[1];
    const float* beta  = (const float*)d_in[2];
    const float* wq = (const float*)d_in[3];
    const float* bq = (const float*)d_in[4];
    const float* wk = (const float*)d_in[5];
    const float* bk = (const float*)d_in[6];
    const float* wv = (const float*)d_in[7];
    const float* bv = (const float*)d_in[8];
    const float* wo = (const float*)d_in[9];
    const float* bo = (const float*)d_in[10];

    char* ws = (char*)d_ws;
    unsigned short* h_t  = (unsigned short*)(ws);                 // [B,N,C] bf16 16MB
    unsigned char*  q_8  = (unsigned char*)(ws + 16777216);       // [B,N,C] fp8
    unsigned char*  k_8  = (unsigned char*)(ws + 33554432);       // [B,N,C] fp8
    unsigned char*  v_8  = (unsigned char*)(ws + 50331648);       // [B,C,N] fp8
    unsigned short* o_t  = (unsigned short*)(ws + 67108864);      // [B,N,C] bf16
    unsigned char*  S    = (unsigned char*)(ws + 83886080);       // [B,N,N] fp8 67MB
    unsigned short* wqb  = (unsigned short*)(ws + 218103808);
    unsigned short* wkb  = (unsigned short*)(ws + 218628096);
    unsigned short* wvb  = (unsigned short*)(ws + 219152384);
    unsigned short* wob  = (unsigned short*)(ws + 219676672);
    float* statm         = (float*)(ws + 220200960);              // [128]
    float* statr         = (float*)(ws + 220201984);              // [128]
    float* lsum          = (float*)(ws + 220203008);              // [B*N] = 16384 floats

    const float SCALE = 0.044194173824159216f; // 512^-0.5

    cvt_kernel<<<256, 256, 0, stream>>>(wq, wqb, 65536);
    cvt_kernel<<<256, 256, 0, stream>>>(wk, wkb, 65536);
    cvt_kernel<<<256, 256, 0, stream>>>(wv, wvb, 65536);
    cvt_kernel<<<256, 256, 0, stream>>>(wo, wob, 65536);
    zero_kernel<<<16, 256, 0, stream>>>(lsum, 4096);

    gn_stats_kernel<<<128, 256, 0, stream>>>(x, statm, statr);
    gn_norm_kernel<<<dim3(64, 8, 4), 256, 0, stream>>>(x, statm, statr, gamma, beta, h_t);

    // q_8 = fp8(h . Wq^T + bq)   [B,N,C]  (scale folded into qk exp)
    gemm_bt<128, 0, 2, 3, 0><<<dim3(4, 32, 4), 256, 0, stream>>>(
        h_t, Cc, NC, wqb, Cc, 0, q_8, Cc, NC, bq, nullptr, 0, Cc, 1.f);
    // k_8 = fp8(h . Wk^T + bk)   [B,N,C]
    gemm_bt<128, 0, 2, 3, 0><<<dim3(4, 32, 4), 256, 0, stream>>>(
        h_t, Cc, NC, wkb, Cc, 0, k_8, Cc, NC, bk, nullptr, 0, Cc, 1.f);
    // v_8 = fp8(Wv . h^T + bv)   [B,C,N]
    gemm_bt<128, 0, 1, 3, 0><<<dim3(32, 4, 4), 256, 0, stream>>>(
        wvb, Cc, 0, h_t, Cc, NC, v_8, Nn, NC, bv, nullptr, 0, Cc, 1.f);

    // S = fp8(exp(q.k^T * scale - 2)); lsum = row sums
    qk_fp8<<<dim3(32, 16, 4), 256, 0, stream>>>(q_8, k_8, S, lsum, SCALE);
    // o_t = (S . V^T) / lsum   bf16 [B,N,C]
    pv_fp8<<<dim3(4, 32, 4), 256, 0, stream>>>(S, v_8, lsum, o_t);

    // out = Wo . o^T + bo + x   fp32 [B,C,N]
    gemm_bt<128, 0, 1, 0, 1><<<dim3(32, 4, 4), 256, 0, stream>>>(
        wob, Cc, 0, o_t, Cc, NC, d_out, Nn, NC, bo, x, NC, Cc, 1.f);
}